// Round 1
// 463.620 us; speedup vs baseline: 1.1071x; 1.1071x over previous
//
#include <hip/hip_runtime.h>
#include <math.h>

// VanillaRNN via MFMA: B=1024, T=512, I=64, H=128, O=10, fp32 in/out.
// R8: producer/consumer wave specialization + rational tanh.
//  - 512 threads = 8 waves. Waves 0-3 (consumers) run the h-recurrence only:
//    barrier -> ds_read h-frags + xproj seed -> 8 MFMAs -> tanh -> packed
//    b32 h-writes -> barrier. No vmem, no vmcnt on the critical path.
//  - Waves 4-7 (producers) compute xproj(t+1)+bias into an LDS ring one step
//    ahead (depth-2 raw-x prefetch, loads never drained by the LDS barrier).
//    One consumer + one producer per SIMD: producer issue fills consumer
//    latency stalls.
//  - tanh via Pade[3/3] z*P(z^2)/Q(z^2) + med3 clamp: 1 transcendental
//    (v_rcp) instead of exp2+rcp, no 2.885 scale mul. |err| <= 1e-4.
//  - Paired-column B-frags: lane c owns columns 32w+2c / 32w+2c+1, so the
//    two tanh results pack into one ds_write_b32 (4 writes vs 8 b16).
//  - Bias folded into the producer MFMA seed.

#define T_STEPS 512
#define I_DIM   64
#define H_DIM   128
#define O_DIM   10
#define BT      16            // batch rows per block
#define PITCH   136           // bf16 elements per h row
#define XPITCH  20            // f32 per xproj row (16 + pad, keeps 16B align)

typedef short  bf16x8 __attribute__((ext_vector_type(8)));
typedef float  f32x4  __attribute__((ext_vector_type(4)));

#define MFMA(A, Bi, C) __builtin_amdgcn_mfma_f32_16x16x32_bf16((A), __builtin_bit_cast(bf16x8, (Bi)), (C), 0, 0, 0)

static __device__ inline short f2bf(float f) {               // full RNE (preload only)
    union { float f; unsigned u; } v; v.f = f;
    unsigned r = v.u + 0x7FFFu + ((v.u >> 16) & 1u);
    return (short)(r >> 16);
}
static __device__ inline int pk2(float a, float b) {         // fast packed round
    unsigned ua = __builtin_bit_cast(unsigned, a);
    unsigned ub = __builtin_bit_cast(unsigned, b);
    return (int)(((ua + 0x8000u) >> 16) | ((ub + 0x8000u) & 0xFFFF0000u));
}
static __device__ inline float bf2f(short s) {
    union { unsigned u; float f; } v; v.u = ((unsigned)(unsigned short)s) << 16;
    return v.f;
}
// tanh via Pade[3/3] continued fraction, clamped. Matches Taylor through x^5;
// abs err <= ~1e-4 for all z (clamp handles |z|>~3.7). One trans op (rcp).
static __device__ inline float pade_tanh(float z) {
    const float t = z * z;
    const float p = fmaf(fmaf(t + 378.0f, t, 17325.0f), t, 135135.0f);
    const float qd = fmaf(fmaf(fmaf(28.0f, t, 3150.0f), t, 62370.0f), t, 135135.0f);
    const float r = (z * p) * __builtin_amdgcn_rcpf(qd);
    return __builtin_amdgcn_fmed3f(r, -1.0f, 1.0f);
}
// Barrier that does NOT drain vmcnt: handoff only needs LDS ops complete.
static __device__ inline void lds_barrier() {
    asm volatile("s_waitcnt lgkmcnt(0)\n\ts_barrier" ::: "memory");
}
static __device__ inline int4 load_frag(const float* src) {  // f32 row -> bf16x8 frag
    short e[8];
    #pragma unroll
    for (int j = 0; j < 8; ++j) e[j] = f2bf(src[j]);
    int4 r;
    r.x = ((int)(unsigned short)e[0]) | ((int)(unsigned short)e[1] << 16);
    r.y = ((int)(unsigned short)e[2]) | ((int)(unsigned short)e[3] << 16);
    r.z = ((int)(unsigned short)e[4]) | ((int)(unsigned short)e[5] << 16);
    r.w = ((int)(unsigned short)e[6]) | ((int)(unsigned short)e[7] << 16);
    return r;
}

// Consumer step: h_{t+1} = tanh(xp + h_t W_hh^T). Reads hbuf[P] + xpb[P],
// writes hbuf[1-P]. Lane (c,q) owns columns n0=32w+2c and n0+1.
#define CONS_STEP(P)                                                            \
    {                                                                           \
        const short* hb = hbuf[P] + c * PITCH + q * 8;                          \
        bf16x8 Ah0 = *(const bf16x8*)(hb +  0);                                 \
        bf16x8 Ah1 = *(const bf16x8*)(hb + 32);                                 \
        bf16x8 Ah2 = *(const bf16x8*)(hb + 64);                                 \
        bf16x8 Ah3 = *(const bf16x8*)(hb + 96);                                 \
        f32x4 Ca0 = *(const f32x4*)&xpb[P][ n0      * XPITCH + 4 * q];          \
        f32x4 Ca1 = *(const f32x4*)&xpb[P][(n0 + 1) * XPITCH + 4 * q];          \
        f32x4 Cb0 = {0.f, 0.f, 0.f, 0.f};                                       \
        f32x4 Cb1 = {0.f, 0.f, 0.f, 0.f};                                       \
        Ca0 = MFMA(Ah0, Bw[0][0], Ca0); Ca1 = MFMA(Ah0, Bw[1][0], Ca1);         \
        Cb0 = MFMA(Ah1, Bw[0][1], Cb0); Cb1 = MFMA(Ah1, Bw[1][1], Cb1);         \
        Ca0 = MFMA(Ah2, Bw[0][2], Ca0); Ca1 = MFMA(Ah2, Bw[1][2], Ca1);         \
        Cb0 = MFMA(Ah3, Bw[0][3], Cb0); Cb1 = MFMA(Ah3, Bw[1][3], Cb1);         \
        const f32x4 C0 = Ca0 + Cb0;                                             \
        const f32x4 C1 = Ca1 + Cb1;                                             \
        short* hw = hbuf[1 - (P)];                                              \
        _Pragma("unroll")                                                       \
        for (int r = 0; r < 4; ++r) {                                           \
            const int m = q * 4 + r;                                            \
            const float h0 = pade_tanh(C0[r]);                                  \
            const float h1 = pade_tanh(C1[r]);                                  \
            *(int*)(hw + m * PITCH + n0) = pk2(h0, h1);                         \
        }                                                                       \
    }

// Producer step during parity P: write xp for step t+1 into xpb[1-P] from XR
// (= x_{t+1}), then reissue XR <- x at time TN (2 steps of vmcnt slack).
#define PROD_STEP(P, XR, TN)                                                    \
    {                                                                           \
        int4 a0, a1;                                                            \
        a0.x = pk2(XR[0].x, XR[0].y); a0.y = pk2(XR[0].z, XR[0].w);             \
        a0.z = pk2(XR[1].x, XR[1].y); a0.w = pk2(XR[1].z, XR[1].w);             \
        a1.x = pk2(XR[2].x, XR[2].y); a1.y = pk2(XR[2].z, XR[2].w);             \
        a1.z = pk2(XR[3].x, XR[3].y); a1.w = pk2(XR[3].z, XR[3].w);             \
        const int tn = ((TN) < T_STEPS) ? (TN) : (T_STEPS - 1);                 \
        const float* pn = xrow + (size_t)tn * I_DIM;                            \
        XR[0] = *(const float4*)(pn +      q * 8);                              \
        XR[1] = *(const float4*)(pn +      q * 8 + 4);                          \
        XR[2] = *(const float4*)(pn + 32 + q * 8);                              \
        XR[3] = *(const float4*)(pn + 32 + q * 8 + 4);                          \
        bf16x8 Ax0 = __builtin_bit_cast(bf16x8, a0);                            \
        bf16x8 Ax1 = __builtin_bit_cast(bf16x8, a1);                            \
        f32x4 P0 = MFMA(Ax0, BX[0][0], biasv[0]);                               \
        P0 = MFMA(Ax1, BX[0][1], P0);                                           \
        f32x4 P1 = MFMA(Ax0, BX[1][0], biasv[1]);                               \
        P1 = MFMA(Ax1, BX[1][1], P1);                                           \
        *(f32x4*)&xpb[1 - (P)][ n0      * XPITCH + 4 * q] = P0;                 \
        *(f32x4*)&xpb[1 - (P)][(n0 + 1) * XPITCH + 4 * q] = P1;                 \
    }

__global__ __launch_bounds__(512, 2)
void rnn_mfma_kernel(
    const float* __restrict__ x,      // [B, T, I]
    const float* __restrict__ W_hx,   // [H, I]
    const float* __restrict__ W_hh,   // [H, H]
    const float* __restrict__ b_hh,   // [H]
    const float* __restrict__ W_ph,   // [O, H]
    const float* __restrict__ b_ph,   // [O]
    float* __restrict__ out)          // [B, O]
{
    const int b0   = blockIdx.x * BT;
    const int tid  = threadIdx.x;
    const int wave = tid >> 6;        // 0-3 consumers, 4-7 producers
    const int lane = tid & 63;
    const int c    = lane & 15;
    const int q    = lane >> 4;
    const int w    = wave & 3;        // N-slice [32w, 32w+32)
    const int n0   = w * 32 + 2 * c;  // paired columns n0, n0+1

    __shared__ __align__(16) short hbuf[2][BT * PITCH];      // bf16 h ping-pong
    __shared__ __align__(16) float xpb[2][H_DIM * XPITCH];   // xproj+bias ring

    // ---- h0 = 0
    for (int idx = tid; idx < BT * PITCH; idx += 512) hbuf[0][idx] = 0;

    if (wave < 4) {
        // ================= consumer =================
        int4 Bw[2][4];   // W_hh B-frags: [nt = column n0+nt][kt]
        #pragma unroll
        for (int nt = 0; nt < 2; ++nt)
            #pragma unroll
            for (int kt = 0; kt < 4; ++kt)
                Bw[nt][kt] = load_frag(W_hh + (n0 + nt) * H_DIM + kt * 32 + q * 8);
        #pragma unroll
        for (int nt = 0; nt < 2; ++nt)
            #pragma unroll
            for (int kt = 0; kt < 4; ++kt)
                asm volatile("" : "+v"(Bw[nt][kt].x), "+v"(Bw[nt][kt].y),
                                  "+v"(Bw[nt][kt].z), "+v"(Bw[nt][kt].w));
        __syncthreads();
        __builtin_amdgcn_s_setprio(1);     // favor the recurrence wave on the SIMD
        #pragma unroll 1
        for (int t = 0; t < T_STEPS; t += 2) {
            CONS_STEP(0)
            lds_barrier();
            CONS_STEP(1)
            lds_barrier();
        }
        __builtin_amdgcn_s_setprio(0);
    } else {
        // ================= producer =================
        int4 BX[2][2];   // W_hx B-frags
        f32x4 biasv[2];
        #pragma unroll
        for (int nt = 0; nt < 2; ++nt) {
            #pragma unroll
            for (int kx = 0; kx < 2; ++kx)
                BX[nt][kx] = load_frag(W_hx + (n0 + nt) * I_DIM + kx * 32 + q * 8);
            const float bb = b_hh[n0 + nt];
            biasv[nt] = (f32x4){bb, bb, bb, bb};
        }
        #pragma unroll
        for (int nt = 0; nt < 2; ++nt)
            #pragma unroll
            for (int kx = 0; kx < 2; ++kx)
                asm volatile("" : "+v"(BX[nt][kx].x), "+v"(BX[nt][kx].y),
                                  "+v"(BX[nt][kx].z), "+v"(BX[nt][kx].w));

        const float* xrow = x + (size_t)(b0 + c) * T_STEPS * I_DIM;
        {   // xp[0] = x_0 W_hx^T + b, before the sync
            float4 x0[4];
            x0[0] = *(const float4*)(xrow +      q * 8);
            x0[1] = *(const float4*)(xrow +      q * 8 + 4);
            x0[2] = *(const float4*)(xrow + 32 + q * 8);
            x0[3] = *(const float4*)(xrow + 32 + q * 8 + 4);
            int4 a0, a1;
            a0.x = pk2(x0[0].x, x0[0].y); a0.y = pk2(x0[0].z, x0[0].w);
            a0.z = pk2(x0[1].x, x0[1].y); a0.w = pk2(x0[1].z, x0[1].w);
            a1.x = pk2(x0[2].x, x0[2].y); a1.y = pk2(x0[2].z, x0[2].w);
            a1.z = pk2(x0[3].x, x0[3].y); a1.w = pk2(x0[3].z, x0[3].w);
            bf16x8 Ax0 = __builtin_bit_cast(bf16x8, a0);
            bf16x8 Ax1 = __builtin_bit_cast(bf16x8, a1);
            f32x4 P0 = MFMA(Ax0, BX[0][0], biasv[0]);
            P0 = MFMA(Ax1, BX[0][1], P0);
            f32x4 P1 = MFMA(Ax0, BX[1][0], biasv[1]);
            P1 = MFMA(Ax1, BX[1][1], P1);
            *(f32x4*)&xpb[0][ n0      * XPITCH + 4 * q] = P0;
            *(f32x4*)&xpb[0][(n0 + 1) * XPITCH + 4 * q] = P1;
        }
        // depth-2 raw-x prefetch: xrA <- x_1, xrB <- x_2
        float4 xrA[4], xrB[4];
        const float* p1 = xrow + I_DIM;
        xrA[0] = *(const float4*)(p1 +      q * 8);
        xrA[1] = *(const float4*)(p1 +      q * 8 + 4);
        xrA[2] = *(const float4*)(p1 + 32 + q * 8);
        xrA[3] = *(const float4*)(p1 + 32 + q * 8 + 4);
        const float* p2 = xrow + 2 * I_DIM;
        xrB[0] = *(const float4*)(p2 +      q * 8);
        xrB[1] = *(const float4*)(p2 +      q * 8 + 4);
        xrB[2] = *(const float4*)(p2 + 32 + q * 8);
        xrB[3] = *(const float4*)(p2 + 32 + q * 8 + 4);
        __syncthreads();
        #pragma unroll 1
        for (int t = 0; t < T_STEPS; t += 2) {
            PROD_STEP(0, xrA, t + 3)   // xp for t+1 from x_{t+1}; reload x_{t+3}
            lds_barrier();
            PROD_STEP(1, xrB, t + 4)   // xp for t+2 from x_{t+2}; reload x_{t+4}
            lds_barrier();
        }
    }

    // ---- Epilogue: final h_512 sits in hbuf[0].
    if (tid < BT * O_DIM) {
        const int m = tid / O_DIM;
        const int o = tid % O_DIM;
        float acc = b_ph[o];
        #pragma unroll 4
        for (int k = 0; k < H_DIM; ++k)
            acc = fmaf(W_ph[o * H_DIM + k], bf2f(hbuf[0][m * PITCH + k]), acc);
        out[(size_t)(b0 + m) * O_DIM + o] = acc;
    }
}

extern "C" void kernel_launch(void* const* d_in, const int* in_sizes, int n_in,
                              void* d_out, int out_size, void* d_ws, size_t ws_size,
                              hipStream_t stream) {
    const float* x    = (const float*)d_in[0];
    const float* W_hx = (const float*)d_in[1];
    const float* W_hh = (const float*)d_in[2];
    const float* b_hh = (const float*)d_in[3];
    const float* W_ph = (const float*)d_in[4];
    const float* b_ph = (const float*)d_in[5];
    float* out = (float*)d_out;

    rnn_mfma_kernel<<<1024 / BT, 512, 0, stream>>>(x, W_hx, W_hh, b_hh, W_ph, b_ph, out);
}